// Round 1
// baseline (355.474 us; speedup 1.0000x reference)
//
#include <hip/hip_runtime.h>

// MultiheadAttentionWithBias: B=2, L=2048, D=1024, H=16, HD=64
// Pipeline: cvt(f32->bf16) -> QKV GEMM (bf16 MFMA) -> V transpose ->
//           flash attention w/ f32 bias -> out-proj GEMM -> f32 out.

typedef __attribute__((ext_vector_type(8))) short bf16x8;
typedef __attribute__((ext_vector_type(4))) float f32x4;
typedef __attribute__((ext_vector_type(8))) unsigned short u16x8;
using u16 = unsigned short;

#define MFMA16(a, b, c) __builtin_amdgcn_mfma_f32_16x16x32_bf16((a), (b), (c), 0, 0, 0)
#define LOG2E 1.44269504088896f
#define QSCALE (0.125f * 1.44269504088896f)

__device__ __forceinline__ u16 f2bf(float f) {
  union { float f; unsigned int u; } v; v.f = f;
  unsigned int r = v.u + 0x7FFFu + ((v.u >> 16) & 1u);
  return (u16)(r >> 16);
}

__device__ __forceinline__ void g2lds16(const void* gsrc, void* ldst) {
  __builtin_amdgcn_global_load_lds(
      (const __attribute__((address_space(1))) unsigned int*)gsrc,
      (__attribute__((address_space(3))) unsigned int*)ldst, 16, 0, 0);
}

// ---------------- f32 -> bf16 convert, 8 elems/thread ----------------
__global__ __launch_bounds__(256) void cvt_kernel(const float* __restrict__ src,
                                                  u16* __restrict__ dst, int n8) {
  int i = blockIdx.x * 256 + threadIdx.x;
  if (i >= n8) return;
  const float4* s = (const float4*)src;
  float4 a = s[2 * i], b = s[2 * i + 1];
  u16x8 o;
  o[0] = f2bf(a.x); o[1] = f2bf(a.y); o[2] = f2bf(a.z); o[3] = f2bf(a.w);
  o[4] = f2bf(b.x); o[5] = f2bf(b.y); o[6] = f2bf(b.z); o[7] = f2bf(b.w);
  ((u16x8*)dst)[i] = o;
}

// ---------------- GEMM C = A * B^T (A:[M,1024] bf16, B:[N,1024] bf16) ----------------
// 128x128 tile, 4 waves (2x2), 16x16x32 MFMA, BK=64, global_load_lds staging.
// MODE 0: epilogue scatters to q/k/v [B,H,L,HD] bf16 (+bias, q scaled).
// MODE 1: epilogue writes f32 out [M,1024] (+bias).
template <int MODE>
__global__ __launch_bounds__(256, 2) void gemm_bt(
    const u16* __restrict__ A, const u16* __restrict__ B,
    u16* __restrict__ qp, u16* __restrict__ kp, u16* __restrict__ vp,
    const float* __restrict__ b0, const float* __restrict__ b1,
    const float* __restrict__ b2, float* __restrict__ outp,
    const float* __restrict__ bo) {
  __shared__ __align__(16) u16 lA[128 * 64];
  __shared__ __align__(16) u16 lB[128 * 64];
  const int tid = threadIdx.x;
  const int lane = tid & 63, wid = tid >> 6;
  const int g = lane >> 4, cc = lane & 15;
  const int wr = wid >> 1, wc = wid & 1;
  const int m0 = blockIdx.y * 128, n0 = blockIdx.x * 128;
  f32x4 acc[4][4] = {};
  for (int kt = 0; kt < 16; ++kt) {
    const int kof = kt * 64;
#pragma unroll
    for (int i = 0; i < 4; ++i) {
      int cid = i * 256 + tid;
      int row = cid >> 3;
      int col = (cid & 7) * 8;
      g2lds16(A + (size_t)(m0 + row) * 1024 + kof + col, &lA[(i * 256 + wid * 64) * 8]);
      g2lds16(B + (size_t)(n0 + row) * 1024 + kof + col, &lB[(i * 256 + wid * 64) * 8]);
    }
    __syncthreads();
#pragma unroll
    for (int kc = 0; kc < 2; ++kc) {
      bf16x8 af[4], bfr[4];
#pragma unroll
      for (int mf = 0; mf < 4; ++mf)
        af[mf] = *(const bf16x8*)&lA[(wr * 64 + mf * 16 + cc) * 64 + kc * 32 + g * 8];
#pragma unroll
      for (int nf = 0; nf < 4; ++nf)
        bfr[nf] = *(const bf16x8*)&lB[(wc * 64 + nf * 16 + cc) * 64 + kc * 32 + g * 8];
#pragma unroll
      for (int mf = 0; mf < 4; ++mf)
#pragma unroll
        for (int nf = 0; nf < 4; ++nf)
          acc[mf][nf] = MFMA16(af[mf], bfr[nf], acc[mf][nf]);
    }
    __syncthreads();
  }
#pragma unroll
  for (int mf = 0; mf < 4; ++mf) {
#pragma unroll
    for (int nf = 0; nf < 4; ++nf) {
      int n = n0 + wc * 64 + nf * 16 + cc;
      if (MODE == 0) {
        int which = n >> 10;
        int nn = n & 1023;
        const float* bp = which == 0 ? b0 : (which == 1 ? b1 : b2);
        u16* dp = which == 0 ? qp : (which == 1 ? kp : vp);
        float bias = bp[nn];
        int h = nn >> 6, hd = nn & 63;
#pragma unroll
        for (int r = 0; r < 4; ++r) {
          int m = m0 + wr * 64 + mf * 16 + g * 4 + r;
          int bb = m >> 11, ll = m & 2047;
          float val = acc[mf][nf][r] + bias;
          if (which == 0) val *= QSCALE;  // fold 1/sqrt(64) * log2(e) into q
          dp[(((size_t)(bb * 16 + h)) * 2048 + ll) * 64 + hd] = f2bf(val);
        }
      } else {
        float bias = bo[n];
#pragma unroll
        for (int r = 0; r < 4; ++r) {
          int m = m0 + wr * 64 + mf * 16 + g * 4 + r;
          outp[(size_t)m * 1024 + n] = acc[mf][nf][r] + bias;
        }
      }
    }
  }
}

// ---------------- V transpose: [BH, L, 64] -> [BH, 64, L] ----------------
__global__ __launch_bounds__(256) void transpose_v(const u16* __restrict__ v,
                                                   u16* __restrict__ vt) {
  __shared__ u16 t[64 * 65];
  const int bh = blockIdx.y, l0 = blockIdx.x * 64;
  const int tid = threadIdx.x;
  const u16* src = v + ((size_t)bh * 2048 + l0) * 64;
#pragma unroll
  for (int it = 0; it < 2; ++it) {
    int idx = it * 256 + tid;
    int r = idx >> 3, c8 = (idx & 7) * 8;
    u16x8 val = *(const u16x8*)&src[r * 64 + c8];
#pragma unroll
    for (int j = 0; j < 8; ++j) t[r * 65 + c8 + j] = val[j];
  }
  __syncthreads();
  u16* dst = vt + (size_t)bh * 64 * 2048 + l0;
#pragma unroll
  for (int it = 0; it < 2; ++it) {
    int d = (tid >> 3) + it * 32;
    int ls = (tid & 7) * 8;
    u16x8 o;
#pragma unroll
    for (int j = 0; j < 8; ++j) o[j] = t[(ls + j) * 65 + d];
    *(u16x8*)&dst[(size_t)d * 2048 + ls] = o;
  }
}

// ---------------- Flash attention ----------------
// Block: 256 thr = 4 waves. wave = (batch b = wid>>1, strip = wid&1).
// Each wave: 16 q-rows of one batch; both batches share the bias tile (L1/L2 reuse).
// q pre-scaled by 0.125*log2e; bias multiplied by log2e -> exp2-domain softmax.
__global__ __launch_bounds__(256, 3) void attn_kernel(
    const u16* __restrict__ qm, const u16* __restrict__ km,
    const u16* __restrict__ vtm, const float* __restrict__ bias,
    u16* __restrict__ aout) {
  __shared__ __align__(16) u16 plds[4 * 16 * 64];  // per-wave 16x64 bf16 P tile
  const int tid = threadIdx.x;
  const int lane = tid & 63, wid = tid >> 6;
  const int g = lane >> 4, cc = lane & 15;
  const int b = wid >> 1, strip = wid & 1;
  const int h = blockIdx.y;
  const int q0 = blockIdx.x * 32 + strip * 16;
  const size_t bh = (size_t)b * 16 + h;
  const u16* qbase = qm + (bh * 2048 + q0) * 64;
  const u16* kbase = km + bh * 2048 * 64;
  const u16* vtbase = vtm + bh * 64 * 2048;
  const float* bbase = bias + ((size_t)h * 2048 + q0) * 2048;
  u16* pl = &plds[wid * 1024];

  bf16x8 qf0 = *(const bf16x8*)&qbase[(size_t)cc * 64 + g * 8];
  bf16x8 qf1 = *(const bf16x8*)&qbase[(size_t)cc * 64 + 32 + g * 8];
  f32x4 o[4] = {};
  float mrow[4], lrow[4];
#pragma unroll
  for (int r = 0; r < 4; ++r) { mrow[r] = -3.0e38f; lrow[r] = 0.f; }

  for (int kt = 0; kt < 32; ++kt) {
    const int k0 = kt * 64;
    // S = Q K^T (already exp2-domain scaled)
    f32x4 s[4];
#pragma unroll
    for (int kb = 0; kb < 4; ++kb) {
      const u16* kr = &kbase[(size_t)(k0 + kb * 16 + cc) * 64 + g * 8];
      bf16x8 kf0 = *(const bf16x8*)kr;
      bf16x8 kf1 = *(const bf16x8*)(kr + 32);
      f32x4 z = {};
      z = MFMA16(qf0, kf0, z);
      z = MFMA16(qf1, kf1, z);
      s[kb] = z;
    }
    // + bias*log2e (THE main HBM stream: 256MB read once, shared across batches)
#pragma unroll
    for (int kb = 0; kb < 4; ++kb)
#pragma unroll
      for (int r = 0; r < 4; ++r) {
        float bv = bbase[(size_t)(g * 4 + r) * 2048 + k0 + kb * 16 + cc];
        s[kb][r] += bv * LOG2E;
      }
    // online softmax: row r lives on 16 lanes (same g); reduce over lane bits 0-3
    float rmax[4];
#pragma unroll
    for (int r = 0; r < 4; ++r)
      rmax[r] = fmaxf(fmaxf(s[0][r], s[1][r]), fmaxf(s[2][r], s[3][r]));
#pragma unroll
    for (int msk = 1; msk <= 8; msk <<= 1)
#pragma unroll
      for (int r = 0; r < 4; ++r)
        rmax[r] = fmaxf(rmax[r], __shfl_xor(rmax[r], msk, 64));
    float sc[4], ps[4];
#pragma unroll
    for (int r = 0; r < 4; ++r) {
      float mnew = fmaxf(mrow[r], rmax[r]);
      sc[r] = __builtin_amdgcn_exp2f(mrow[r] - mnew);
      mrow[r] = mnew;
    }
#pragma unroll
    for (int kb = 0; kb < 4; ++kb)
#pragma unroll
      for (int r = 0; r < 4; ++r)
        s[kb][r] = __builtin_amdgcn_exp2f(s[kb][r] - mrow[r]);
#pragma unroll
    for (int r = 0; r < 4; ++r)
      ps[r] = (s[0][r] + s[1][r]) + (s[2][r] + s[3][r]);
#pragma unroll
    for (int msk = 1; msk <= 8; msk <<= 1)
#pragma unroll
      for (int r = 0; r < 4; ++r)
        ps[r] += __shfl_xor(ps[r], msk, 64);
#pragma unroll
    for (int r = 0; r < 4; ++r)
      lrow[r] = lrow[r] * sc[r] + ps[r];
#pragma unroll
    for (int td = 0; td < 4; ++td)
#pragma unroll
      for (int r = 0; r < 4; ++r)
        o[td][r] *= sc[r];
    // P -> LDS (wave-private, XOR-swizzled 16B chunks to kill bank conflicts)
#pragma unroll
    for (int kb = 0; kb < 4; ++kb)
#pragma unroll
      for (int r = 0; r < 4; ++r) {
        int row = g * 4 + r;
        int pc = (kb * 2 + (cc >> 3)) ^ (row & 7);
        pl[row * 64 + pc * 8 + (cc & 7)] = f2bf(s[kb][r]);
      }
    bf16x8 pf0, pf1;
    {
      int pc0 = (g) ^ (cc & 7);
      int pc1 = (4 + g) ^ (cc & 7);
      pf0 = *(const bf16x8*)&pl[cc * 64 + pc0 * 8];
      pf1 = *(const bf16x8*)&pl[cc * 64 + pc1 * 8];
    }
    // O += P V   (V^T rows are contiguous k)
#pragma unroll
    for (int td = 0; td < 4; ++td) {
      const u16* vr = &vtbase[(size_t)(td * 16 + cc) * 2048 + k0 + g * 8];
      bf16x8 vf0 = *(const bf16x8*)vr;
      bf16x8 vf1 = *(const bf16x8*)(vr + 32);
      o[td] = MFMA16(pf0, vf0, o[td]);
      o[td] = MFMA16(pf1, vf1, o[td]);
    }
  }
  // normalize + write attn output [B, L, 1024] bf16
#pragma unroll
  for (int td = 0; td < 4; ++td)
#pragma unroll
    for (int r = 0; r < 4; ++r) {
      float val = o[td][r] / lrow[r];
      int qg = q0 + g * 4 + r;
      aout[((size_t)b * 2048 + qg) * 1024 + h * 64 + td * 16 + cc] = f2bf(val);
    }
}

extern "C" void kernel_launch(void* const* d_in, const int* in_sizes, int n_in,
                              void* d_out, int out_size, void* d_ws, size_t ws_size,
                              hipStream_t stream) {
  const float* x  = (const float*)d_in[0];
  const float* rb = (const float*)d_in[1];
  const float* Wq = (const float*)d_in[2];
  const float* bq = (const float*)d_in[3];
  const float* Wk = (const float*)d_in[4];
  const float* bk = (const float*)d_in[5];
  const float* Wv = (const float*)d_in[6];
  const float* bv = (const float*)d_in[7];
  const float* Wo = (const float*)d_in[8];
  const float* bo = (const float*)d_in[9];
  float* out = (float*)d_out;
  char* ws = (char*)d_ws;

  u16* xb   = (u16*)(ws);                 // 8 MB  [4096,1024] bf16 (reused as aout)
  u16* W1b  = (u16*)(ws + (8 << 20));     // 6 MB  [3072,1024] bf16 (Wq|Wk|Wv)
  u16* Wob  = (u16*)(ws + (14 << 20));    // 2 MB  [1024,1024] bf16
  u16* qb   = (u16*)(ws + (16 << 20));    // 8 MB  [B,H,L,HD]
  u16* kb2  = (u16*)(ws + (24 << 20));    // 8 MB
  u16* vb   = (u16*)(ws + (32 << 20));    // 8 MB
  u16* vtb  = (u16*)(ws + (40 << 20));    // 8 MB  [B,H,HD,L]
  u16* aout = xb;                         // alias: xb dead after QKV GEMM

  cvt_kernel<<<2048, 256, 0, stream>>>(x, xb, 524288);
  cvt_kernel<<<512, 256, 0, stream>>>(Wq, W1b, 131072);
  cvt_kernel<<<512, 256, 0, stream>>>(Wk, W1b + (1 << 20), 131072);
  cvt_kernel<<<512, 256, 0, stream>>>(Wv, W1b + (2 << 20), 131072);
  cvt_kernel<<<512, 256, 0, stream>>>(Wo, Wob, 131072);

  gemm_bt<0><<<dim3(24, 32), 256, 0, stream>>>(xb, W1b, qb, kb2, vb, bq, bk, bv,
                                               nullptr, nullptr);
  transpose_v<<<dim3(32, 32), 256, 0, stream>>>(vb, vtb);
  attn_kernel<<<dim3(64, 16), 256, 0, stream>>>(qb, kb2, vtb, rb, aout);
  gemm_bt<1><<<dim3(8, 32), 256, 0, stream>>>(aout, Wob, nullptr, nullptr, nullptr,
                                              nullptr, nullptr, nullptr, out, bo);
}